// Round 10
// baseline (348.341 us; speedup 1.0000x reference)
//
#include <hip/hip_runtime.h>
#include <cstdint>
#include <cstddef>

#define B_N   16
#define A_N   8732
#define C_N   91
#define FG_N  90
#define K_TOP 400
#define D_N   200
#define NTASK (B_N * FG_N)   // 1440
#define K1_APB 128           // anchors per block in k1
#define K1_NBLK ((A_N + K1_APB - 1) / K1_APB)   // 69

// ---------------------------------------------------------------------------
// K1: softmax + decode, LDS-staged (coalesced float4 slab load, expf once).
// ---------------------------------------------------------------------------
__global__ __launch_bounds__(128) void k1_softmax_decode(
    const float* __restrict__ cls, const float* __restrict__ reg,
    const float* __restrict__ anc, float* __restrict__ probs_t,
    float* __restrict__ boxes)
{
#pragma clang fp contract(off)
  __shared__ float4 lds4[(K1_APB * C_N + 3) / 4];   // 46.6 KB
  float* lds = (float*)lds4;
  const int bb = blockIdx.x;
  const int b = bb / K1_NBLK;
  const int blk = bb - b * K1_NBLK;
  const int a0 = blk * K1_APB;
  const int nloc = (A_N - a0) < K1_APB ? (A_N - a0) : K1_APB;
  const int tid = threadIdx.x;

  const size_t gbase_f4 = ((size_t)(b * A_N + a0) * C_N) >> 2;
  const size_t TOT_F4 = ((size_t)B_N * A_N * C_N) >> 2;
  const float4* cls4 = (const float4*)cls;
  constexpr int NF4 = (K1_APB * C_N) / 4;           // 2912
  for (int i = tid; i < NF4; i += K1_APB) {
    size_t g = gbase_f4 + i;
    if (g < TOT_F4) lds4[i] = cls4[g];
  }
  __syncthreads();

  if (tid >= nloc) return;
  const int a = a0 + tid;
  const int tg = b * A_N + a;
  float* lg = lds + tid * C_N;

  float m = lg[0];
  for (int c = 1; c < C_N; ++c) m = fmaxf(m, lg[c]);
  float s = 0.0f;
  for (int c = 0; c < C_N; ++c) {
    float e = expf(lg[c] - m);
    s += e;
    lg[c] = e;
  }
  for (int c = 1; c < C_N; ++c)
    probs_t[((size_t)b * FG_N + (c - 1)) * A_N + a] = lg[c] / s;

  float4 rl = *(const float4*)(reg + (size_t)tg * 4);
  float4 an = *(const float4*)(anc + (size_t)a * 4);
  float wa = an.z - an.x;
  float ha = an.w - an.y;
  float cxa = an.x + 0.5f * wa;
  float cya = an.y + 0.5f * ha;
  float dx = rl.x / 10.0f;
  float dy = rl.y / 10.0f;
  const float clipv = 4.135166556742356f;   // log(1000/16)
  float dw = fminf(rl.z / 5.0f, clipv);
  float dh = fminf(rl.w / 5.0f, clipv);
  float t1 = dx * wa;  float cx = t1 + cxa;
  float t2 = dy * ha;  float cy = t2 + cya;
  float w = expf(dw) * wa;
  float h = expf(dh) * ha;
  float4 out;
  out.x = fminf(fmaxf(cx - 0.5f * w, 0.0f), 300.0f);
  out.y = fminf(fmaxf(cy - 0.5f * h, 0.0f), 300.0f);
  out.z = fminf(fmaxf(cx + 0.5f * w, 0.0f), 300.0f);
  out.w = fminf(fmaxf(cy + 0.5f * h, 0.0f), 300.0f);
  *(float4*)(boxes + (size_t)tg * 4) = out;
}

// ---------------------------------------------------------------------------
// shared helper: descending rank-select over a 256-chunked histogram
// ---------------------------------------------------------------------------
__device__ __forceinline__ void scan_select(int* hist, int nbins, int need,
                                            int tid, int* chunk, int* res)
{
  int per = nbins >> 8;            // 4096 -> 16, 256 -> 1
  int s = 0;
  for (int i = 0; i < per; ++i) s += hist[tid * per + i];
  chunk[tid] = s;
  __syncthreads();
  if (tid == 0) {
    int cum = 0;
    for (int t2 = 255; t2 >= 0; --t2) { int v = chunk[t2]; chunk[t2] = cum; cum += v; }
  }
  __syncthreads();
  int cum = chunk[tid];            // count in strictly-higher chunks
  for (int i = per - 1; i >= 0; --i) {
    int bn = tid * per + i;
    int h = hist[bn];
    if (cum < need && need <= cum + h) { res[0] = bn; res[1] = cum; }
    cum += h;
  }
  __syncthreads();
}

// ---------------------------------------------------------------------------
// K2: exact top-400 per (image, fg-class) via low-LDS histogram rank-scatter
//     (monotone 12-bit bin = float bits [25:14] for scores in (0.01, 1]).
//     Legacy radix+bitonic fallback if a needed bin straddles slot 1024.
// ---------------------------------------------------------------------------
__global__ __launch_bounds__(256) void k2_topk(
    const float* __restrict__ probs_t, int* __restrict__ topk_anchor,
    float* __restrict__ topk_score, int* __restrict__ topk_cnt)
{
  __shared__ int cnt[4096];                      // 16.4 KB: counts->bases->ends
  __shared__ unsigned long long sorted[1024];    //  8.2 KB
  __shared__ int chunk[256];                     //  1 KB
  __shared__ int res[2];
  __shared__ int s_total;
  __shared__ int s_bad;
  __shared__ int s_lcnt;
  const int task = blockIdx.x;
  const int tid = threadIdx.x;
  const float* sc = probs_t + (size_t)task * A_N;

  for (int i = tid; i < 4096; i += 256) cnt[i] = 0;
  if (tid == 0) s_bad = 0;
  __syncthreads();

  for (int a = tid; a < A_N; a += 256) {
    float p = sc[a];
    if (p > 0.01f)
      atomicAdd(&cnt[(__float_as_uint(p) >> 14) & 0xFFFu], 1);
  }
  __syncthreads();
  {
    int s = 0;
    for (int i = 0; i < 16; ++i) s += cnt[tid * 16 + i];
    chunk[tid] = s;
  }
  __syncthreads();
  if (tid == 0) {
    int run = 0;
    for (int c = 255; c >= 0; --c) { int v = chunk[c]; chunk[c] = run; run += v; }
    s_total = run;
  }
  __syncthreads();
  {
    int acc = chunk[tid];
    for (int i = 15; i >= 0; --i) {
      int bn = tid * 16 + i;
      int h = cnt[bn];
      cnt[bn] = acc;
      acc += h;
    }
  }
  __syncthreads();
  const int total = s_total;
  const int ksel = total < K_TOP ? total : K_TOP;

  for (int a = tid; a < A_N; a += 256) {
    float p = sc[a];
    if (p > 0.01f) {
      unsigned k = __float_as_uint(p);
      int pos = atomicAdd(&cnt[(k >> 14) & 0xFFFu], 1);
      if (pos < 1024)
        sorted[pos] = ((unsigned long long)k << 32) | (unsigned)(0xFFFFFFFFu - (unsigned)a);
    }
  }
  __syncthreads();
  for (int i = 0; i < 16; ++i) {
    int bn = tid * 16 + i;
    int end0 = cnt[bn];
    int start = (bn < 4095) ? cnt[bn + 1] : 0;
    int cb = end0 - start;
    if (cb > 1 && start < K_TOP) {
      if (end0 > 1024) { s_bad = 1; continue; }
      for (int q = start + 1; q < end0; ++q) {
        unsigned long long v = sorted[q];
        int j = q - 1;
        while (j >= start && sorted[j] < v) { sorted[j + 1] = sorted[j]; --j; }
        sorted[j + 1] = v;
      }
    }
  }
  __syncthreads();

  if (s_bad) {
    for (int i = tid; i < 4096; i += 256) cnt[i] = 0;
    __syncthreads();
    for (int a = tid; a < A_N; a += 256) {
      float p = sc[a];
      if (p > 0.01f) atomicAdd(&cnt[__float_as_uint(p) >> 20], 1);
    }
    __syncthreads();
    int need = K_TOP;
    scan_select(cnt, 4096, need, tid, chunk, res);
    const unsigned b1 = (unsigned)res[0];
    const int above1 = res[1];
    const int in1 = cnt[b1];
    __syncthreads();
    unsigned cutoff;
    if (above1 + in1 <= 1024) {
      cutoff = b1 << 20;
    } else {
      need -= above1;
      for (int i = tid; i < 4096; i += 256) cnt[i] = 0;
      __syncthreads();
      for (int a = tid; a < A_N; a += 256) {
        float p = sc[a];
        if (p > 0.01f) {
          unsigned k = __float_as_uint(p);
          if ((k >> 20) == b1) atomicAdd(&cnt[(k >> 8) & 0xFFFu], 1);
        }
      }
      __syncthreads();
      scan_select(cnt, 4096, need, tid, chunk, res);
      const unsigned b2 = (unsigned)res[0];
      need -= res[1];
      const unsigned pre12 = (b1 << 12) | b2;
      __syncthreads();
      cnt[tid] = 0;
      __syncthreads();
      for (int a = tid; a < A_N; a += 256) {
        float p = sc[a];
        if (p > 0.01f) {
          unsigned k = __float_as_uint(p);
          if ((k >> 8) == pre12) atomicAdd(&cnt[k & 0xFFu], 1);
        }
      }
      __syncthreads();
      scan_select(cnt, 256, need, tid, chunk, res);
      cutoff = (pre12 << 8) | (unsigned)res[0];
      __syncthreads();
    }
    if (tid == 0) s_lcnt = 0;
    __syncthreads();
    for (int a = tid; a < A_N; a += 256) {
      float p = sc[a];
      if (p > 0.01f) {
        unsigned k = __float_as_uint(p);
        if (k >= cutoff) {
          int pos = atomicAdd(&s_lcnt, 1);
          if (pos < 1024)
            sorted[pos] = ((unsigned long long)k << 32) | (unsigned)(0xFFFFFFFFu - (unsigned)a);
        }
      }
    }
    __syncthreads();
    const int n = s_lcnt < 1024 ? s_lcnt : 1024;
    const int W = (n <= 512) ? 512 : 1024;
    for (int i = tid; i < W; i += 256) if (i >= n) sorted[i] = 0ULL;
    __syncthreads();
    for (int kk = 2; kk <= W; kk <<= 1) {
      for (int jj = kk >> 1; jj > 0; jj >>= 1) {
        for (int i = tid; i < W; i += 256) {
          int ix = i ^ jj;
          if (ix > i) {
            unsigned long long va = sorted[i], vb = sorted[ix];
            bool desc = ((i & kk) == 0);
            if (desc ? (va < vb) : (va > vb)) { sorted[i] = vb; sorted[ix] = va; }
          }
        }
        __syncthreads();
      }
    }
  }

  for (int r = tid; r < K_TOP; r += 256) {
    int anchor = 0;
    float scv = -1.0f;
    if (r < ksel) {
      unsigned long long v = sorted[r];
      anchor = (int)(0xFFFFFFFFu - (unsigned)(v & 0xFFFFFFFFull));
      scv = __uint_as_float((unsigned)(v >> 32));
    }
    topk_anchor[(size_t)task * K_TOP + r] = anchor;
    topk_score[(size_t)task * K_TOP + r] = scv;
  }
  if (tid == 0) topk_cnt[task] = ksel;
}

// ---------------------------------------------------------------------------
// K3: chunked greedy NMS, one BLOCK (4 waves) per (image,class).
//     Per chunk: waves 1-3 run the kept-test (strided by 3); wave 0
//     concurrently computes the intra-chunk suppression COLUMNS with a
//     chain-free j-loop (broadcast LDS box, one ballot per j; lane j keeps
//     col_j = {i>j suppressed by j}). Resolve is then pure bit-ops:
//     j=ffs(todo); todo &= ~shfl(mycol,j) — ~35 cyc/iter, no FP chain.
//     IoU decisions bit-match the reference (same operand order,
//     division-free compare + wave-uniform exact-div fallback band).
// ---------------------------------------------------------------------------
__global__ __launch_bounds__(256) void k3_nms(
    const float* __restrict__ boxes, const int* __restrict__ topk_anchor,
    const float* __restrict__ topk_score, const int* __restrict__ topk_cnt,
    unsigned long long* __restrict__ kept_key, int* __restrict__ kept_cnt)
{
#pragma clang fp contract(off)
  __shared__ float4 chunkb[64];                 // 1 KB: wave 0's staging
  __shared__ float4 keptb[D_N];
  __shared__ float  kepta[D_N];
  __shared__ int    keptr[D_N];
  __shared__ unsigned long long s_supm[4];
  __shared__ int s_nk;
  const int task = blockIdx.x;
  const int wid  = threadIdx.x >> 6;
  const int lane = threadIdx.x & 63;
  const int b = task / FG_N;
  const int c = task - b * FG_N;
  const float off = (float)(c + 1) * 302.0f;
  const int cnt = topk_cnt[task];
  const int* ta = topk_anchor + (size_t)task * K_TOP;
  const float* ts = topk_score + (size_t)task * K_TOP;
  const float* bx = boxes + (size_t)b * (A_N * 4);

  if (threadIdx.x == 0) s_nk = 0;
  __syncthreads();

  float4 nxt = make_float4(0.0f, 0.0f, 0.0f, 0.0f);
  if (lane < cnt) nxt = *(const float4*)(bx + (size_t)ta[lane] * 4);

  for (int c0 = 0; c0 < cnt; c0 += 64) {
    float4 cur = nxt;
    int nidx = c0 + 64 + lane;
    if (nidx < cnt) nxt = *(const float4*)(bx + (size_t)ta[nidx] * 4);
    const int rem = cnt - c0;                   // candidates in this chunk
    cur.x += off; cur.y += off; cur.z += off; cur.w += off;
    const float area = (cur.z - cur.x) * (cur.w - cur.y);
    const int nk = s_nk;                        // stable since last barrier

    unsigned long long mycol = 0ULL;
    if (wid > 0) {
      // kept-test, strided across waves 1..3
      bool sup = false;
      for (int k = wid - 1; k < nk; k += 3) {
        float4 kb = keptb[k];
        float  ka = kepta[k];
        float ix1 = fmaxf(cur.x, kb.x);
        float iy1 = fmaxf(cur.y, kb.y);
        float ix2 = fminf(cur.z, kb.z);
        float iy2 = fminf(cur.w, kb.w);
        float inter = fmaxf(ix2 - ix1, 0.0f) * fmaxf(iy2 - iy1, 0.0f);
        float denom = ka + area - inter + 1e-9f;
        float thr = 0.45f * denom;
        bool s_sup = inter > thr;
        bool amb = fabsf(inter - thr) <= 1.5e-6f * thr;
        if (__ballot(amb)) {
          if (amb) s_sup = (inter / denom) > 0.45f;
        }
        sup = sup || s_sup;
      }
      s_supm[wid] = __ballot(sup);
    } else {
      // intra-chunk suppression columns (chain-free)
      chunkb[lane] = cur;
      const int jend = rem < 64 ? rem : 64;
      for (int j = 0; j < jend; ++j) {
        float4 bj = chunkb[j];                  // broadcast read
        float ja = (bj.z - bj.x) * (bj.w - bj.y);   // == lane j's area, exact
        float ix1 = fmaxf(cur.x, bj.x);
        float iy1 = fmaxf(cur.y, bj.y);
        float ix2 = fminf(cur.z, bj.z);
        float iy2 = fminf(cur.w, bj.w);
        float inter = fmaxf(ix2 - ix1, 0.0f) * fmaxf(iy2 - iy1, 0.0f);
        float denom = ja + area - inter + 1e-9f;
        float thr = 0.45f * denom;
        const bool act = (lane > j) && (lane < rem);
        bool s_sup = inter > thr;
        bool amb = (fabsf(inter - thr) <= 1.5e-6f * thr) && act;
        if (__ballot(amb)) {
          if (amb) s_sup = (inter / denom) > 0.45f;
        }
        s_sup = s_sup && act;
        unsigned long long colj = __ballot(s_sup);
        if (lane == j) mycol = colj;
      }
    }
    __syncthreads();

    if (wid == 0) {
      const unsigned long long validm =
          (rem >= 64) ? ~0ULL : ((1ULL << rem) - 1ULL);
      unsigned long long todo =
          validm & ~(s_supm[1] | s_supm[2] | s_supm[3]);
      unsigned long long surv = 0ULL;
      int ns = 0;
      const int room = D_N - nk;
      while (todo) {
        if (ns == room) break;
        int j = __ffsll((unsigned long long)todo) - 1;
        surv |= 1ULL << j;
        ++ns;
        todo &= ~(1ULL << j);
        unsigned long long colj = __shfl(mycol, j);
        todo &= ~colj;
      }
      if ((surv >> lane) & 1ULL) {
        int my = nk + __popcll(surv & ((1ULL << lane) - 1ULL));
        keptb[my] = cur;
        kepta[my] = area;
        keptr[my] = c0 + lane;
      }
      if (lane == 0) s_nk = nk + ns;
    }
    __syncthreads();
    if (s_nk >= D_N) break;
  }

  const int nkf = s_nk;
  for (int k = threadIdx.x; k < nkf; k += 256) {
    int r = keptr[k];
    unsigned sb = __float_as_uint(ts[r]);
    kept_key[(size_t)task * D_N + k] =
        ((unsigned long long)sb << 32) |
        (unsigned)(0xFFFFFFFFu - (unsigned)(c * K_TOP + r));
  }
  if (threadIdx.x == 0) kept_cnt[task] = nkf;
}

// ---------------------------------------------------------------------------
// K4: per-image global pick selection = parallel top-200 of survivor keys.
// ---------------------------------------------------------------------------
__global__ __launch_bounds__(256) void k4_sel(
    const unsigned long long* __restrict__ kept_key,
    const int* __restrict__ kept_cnt, int* __restrict__ pick_flat)
{
  __shared__ int hist[4096];
  __shared__ int chunk[256];
  __shared__ int res[2];
  __shared__ int s_lcnt;
  __shared__ int s_cnts[FG_N];
  __shared__ unsigned long long lst[1024];
  const int b = blockIdx.x;
  const int tid = threadIdx.x;
  const unsigned long long* kb = kept_key + (size_t)b * FG_N * D_N;

  if (tid < FG_N) s_cnts[tid] = kept_cnt[b * FG_N + tid];
  for (int i = tid; i < 4096; i += 256) hist[i] = 0;
  if (tid == 0) s_lcnt = 0;
  __syncthreads();

  for (int idx = tid; idx < FG_N * D_N; idx += 256) {
    int c = idx / D_N, r = idx - c * D_N;
    if (r < s_cnts[c]) {
      unsigned long long k = kb[idx];
      atomicAdd(&hist[(int)(k >> 52)], 1);
      atomicAdd(&s_lcnt, 1);
    }
  }
  __syncthreads();
  const int total = s_lcnt;
  const int npick = total < D_N ? total : D_N;
  unsigned cutoff32 = 1u;
  if (total > D_N) {
    int need = D_N;
    scan_select(hist, 4096, need, tid, chunk, res);
    const unsigned b1 = (unsigned)res[0];
    const int above1 = res[1];
    const int in1 = hist[b1];
    __syncthreads();
    if (above1 + in1 <= 1024) {
      cutoff32 = b1 << 20;
    } else {
      need -= above1;
      for (int i = tid; i < 4096; i += 256) hist[i] = 0;
      __syncthreads();
      for (int idx = tid; idx < FG_N * D_N; idx += 256) {
        int c = idx / D_N, r = idx - c * D_N;
        if (r < s_cnts[c]) {
          unsigned long long k = kb[idx];
          if ((unsigned)(k >> 52) == b1)
            atomicAdd(&hist[(int)((k >> 40) & 0xFFFull)], 1);
        }
      }
      __syncthreads();
      scan_select(hist, 4096, need, tid, chunk, res);
      const unsigned b2 = (unsigned)res[0];
      need -= res[1];
      const unsigned pre12 = (b1 << 12) | b2;
      __syncthreads();
      hist[tid] = 0;
      __syncthreads();
      for (int idx = tid; idx < FG_N * D_N; idx += 256) {
        int c = idx / D_N, r = idx - c * D_N;
        if (r < s_cnts[c]) {
          unsigned long long k = kb[idx];
          if ((unsigned)(k >> 40) == pre12)
            atomicAdd(&hist[(int)((k >> 32) & 0xFFull)], 1);
        }
      }
      __syncthreads();
      scan_select(hist, 256, need, tid, chunk, res);
      cutoff32 = (pre12 << 8) | (unsigned)res[0];
      __syncthreads();
    }
  }
  if (tid == 0) s_lcnt = 0;
  __syncthreads();
  const unsigned long long cutkey = (unsigned long long)cutoff32 << 32;
  for (int idx = tid; idx < FG_N * D_N; idx += 256) {
    int c = idx / D_N, r = idx - c * D_N;
    if (r < s_cnts[c]) {
      unsigned long long k = kb[idx];
      if (k >= cutkey) {
        int pos = atomicAdd(&s_lcnt, 1);
        if (pos < 1024) lst[pos] = k;
      }
    }
  }
  __syncthreads();
  const int n = s_lcnt < 1024 ? s_lcnt : 1024;
  const int W = (n <= 256) ? 256 : (n <= 512) ? 512 : 1024;
  for (int i = tid; i < W; i += 256) if (i >= n) lst[i] = 0ULL;
  __syncthreads();
  for (int kk = 2; kk <= W; kk <<= 1) {
    for (int jj = kk >> 1; jj > 0; jj >>= 1) {
      for (int i = tid; i < W; i += 256) {
        int ix = i ^ jj;
        if (ix > i) {
          unsigned long long va = lst[i], vb = lst[ix];
          bool desc = ((i & kk) == 0);
          if (desc ? (va < vb) : (va > vb)) { lst[i] = vb; lst[ix] = va; }
        }
      }
      __syncthreads();
    }
  }
  for (int i = tid; i < D_N; i += 256) {
    int v = -1;
    if (i < npick)
      v = (int)(0xFFFFFFFFu - (unsigned)(lst[i] & 0xFFFFFFFFull));
    pick_flat[b * D_N + i] = v;
  }
}

// ---------------------------------------------------------------------------
// K5: one wave per pick; packed u64 butterfly top-2 over 90 classes.
// ---------------------------------------------------------------------------
__global__ __launch_bounds__(256) void k5_out(
    const float* __restrict__ probs_t, const float* __restrict__ boxes,
    const int* __restrict__ topk_anchor, const int* __restrict__ pick_flat,
    float* __restrict__ out)
{
  const int wid  = threadIdx.x >> 6;
  const int lane = threadIdx.x & 63;
  const int pick = blockIdx.x * 4 + wid;
  const int b = pick / D_N;
  float* ob = out + (size_t)pick * 4;
  float* os = out + (size_t)B_N * D_N * 4 + (size_t)pick * 2;
  float* ol = out + (size_t)B_N * D_N * 6 + (size_t)pick * 2;
  const int flat = pick_flat[pick];
  if (flat < 0) {
    if (lane == 0) {
      ob[0] = 0.0f; ob[1] = 0.0f; ob[2] = 0.0f; ob[3] = 0.0f;
      os[0] = 0.0f; os[1] = 0.0f;
      ol[0] = 0.0f; ol[1] = 0.0f;
    }
    return;
  }
  const int c = flat / K_TOP;
  const int r = flat - c * K_TOP;
  const int anchor = topk_anchor[((size_t)b * FG_N + c) * K_TOP + r];
  const float* pp = probs_t + (size_t)b * FG_N * A_N + anchor;

  unsigned long long hi, lo = 0ULL;
  {
    float p = pp[(size_t)lane * A_N];
    hi = ((unsigned long long)__float_as_uint(p) << 32) | (0xFFFFFFFFu - (unsigned)lane);
  }
  if (lane + 64 < FG_N) {
    float p = pp[(size_t)(lane + 64) * A_N];
    unsigned long long k2 = ((unsigned long long)__float_as_uint(p) << 32) |
                            (0xFFFFFFFFu - (unsigned)(lane + 64));
    if (k2 > hi) { lo = hi; hi = k2; } else lo = k2;
  }
#pragma unroll
  for (int d = 1; d < 64; d <<= 1) {
    unsigned long long oh = __shfl_xor(hi, d, 64);
    unsigned long long ol2 = __shfl_xor(lo, d, 64);
    unsigned long long nh = hi > oh ? hi : oh;
    unsigned long long mn = hi > oh ? oh : hi;
    unsigned long long ml = lo > ol2 ? lo : ol2;
    hi = nh;
    lo = mn > ml ? mn : ml;
  }
  if (lane == 0) {
    float4 bp = *(const float4*)(boxes + ((size_t)b * A_N + anchor) * 4);
    *(float4*)ob = bp;
    unsigned cc1 = 0xFFFFFFFFu - (unsigned)(hi & 0xFFFFFFFFull);
    unsigned cc2 = 0xFFFFFFFFu - (unsigned)(lo & 0xFFFFFFFFull);
    os[0] = __uint_as_float((unsigned)(hi >> 32));
    os[1] = __uint_as_float((unsigned)(lo >> 32));
    ol[0] = (float)(cc1 + 1);
    ol[1] = (float)(cc2 + 1);
  }
}

// ---------------------------------------------------------------------------
extern "C" void kernel_launch(void* const* d_in, const int* in_sizes, int n_in,
                              void* d_out, int out_size, void* d_ws, size_t ws_size,
                              hipStream_t stream)
{
  (void)in_sizes; (void)n_in; (void)out_size; (void)ws_size;
  const float* cls = (const float*)d_in[0];
  const float* reg = (const float*)d_in[1];
  const float* anc = (const float*)d_in[2];

  char* w = (char*)d_ws;
  size_t off = 0;
  auto carve = [&](size_t bytes) -> char* {
    char* p = w + off;
    off += (bytes + 255) & ~(size_t)255;
    return p;
  };
  float* probs_t                = (float*)carve((size_t)B_N * FG_N * A_N * 4);
  float* boxes                  = (float*)carve((size_t)B_N * A_N * 4 * 4);
  int* topk_anchor              = (int*)carve((size_t)NTASK * K_TOP * 4);
  float* topk_score             = (float*)carve((size_t)NTASK * K_TOP * 4);
  int* topk_cnt                 = (int*)carve((size_t)NTASK * 4);
  unsigned long long* kept_key  = (unsigned long long*)carve((size_t)NTASK * D_N * 8);
  int* kept_cnt                 = (int*)carve((size_t)NTASK * 4);
  int* pick_flat                = (int*)carve((size_t)B_N * D_N * 4);

  hipLaunchKernelGGL(k1_softmax_decode, dim3(B_N * K1_NBLK), dim3(K1_APB), 0, stream,
                     cls, reg, anc, probs_t, boxes);
  hipLaunchKernelGGL(k2_topk, dim3(NTASK), dim3(256), 0, stream,
                     probs_t, topk_anchor, topk_score, topk_cnt);
  hipLaunchKernelGGL(k3_nms, dim3(NTASK), dim3(256), 0, stream,
                     boxes, topk_anchor, topk_score, topk_cnt, kept_key, kept_cnt);
  hipLaunchKernelGGL(k4_sel, dim3(B_N), dim3(256), 0, stream,
                     kept_key, kept_cnt, pick_flat);
  hipLaunchKernelGGL(k5_out, dim3(B_N * D_N / 4), dim3(256), 0, stream,
                     probs_t, boxes, topk_anchor, pick_flat, (float*)d_out);
}

// Round 11
// 322.359 us; speedup vs baseline: 1.0806x; 1.0806x over previous
//
#include <hip/hip_runtime.h>
#include <cstdint>
#include <cstddef>

#define B_N   16
#define A_N   8732
#define C_N   91
#define FG_N  90
#define K_TOP 400
#define D_N   200
#define NTASK (B_N * FG_N)   // 1440
#define K1_APB 128           // anchors per block in k1
#define K1_NBLK ((A_N + K1_APB - 1) / K1_APB)   // 69

// ---------------------------------------------------------------------------
// K1: softmax + decode, LDS-staged (coalesced float4 slab load, expf once).
// ---------------------------------------------------------------------------
__global__ __launch_bounds__(128) void k1_softmax_decode(
    const float* __restrict__ cls, const float* __restrict__ reg,
    const float* __restrict__ anc, float* __restrict__ probs_t,
    float* __restrict__ boxes)
{
#pragma clang fp contract(off)
  __shared__ float4 lds4[(K1_APB * C_N + 3) / 4];   // 46.6 KB
  float* lds = (float*)lds4;
  const int bb = blockIdx.x;
  const int b = bb / K1_NBLK;
  const int blk = bb - b * K1_NBLK;
  const int a0 = blk * K1_APB;
  const int nloc = (A_N - a0) < K1_APB ? (A_N - a0) : K1_APB;
  const int tid = threadIdx.x;

  const size_t gbase_f4 = ((size_t)(b * A_N + a0) * C_N) >> 2;
  const size_t TOT_F4 = ((size_t)B_N * A_N * C_N) >> 2;
  const float4* cls4 = (const float4*)cls;
  constexpr int NF4 = (K1_APB * C_N) / 4;           // 2912
  for (int i = tid; i < NF4; i += K1_APB) {
    size_t g = gbase_f4 + i;
    if (g < TOT_F4) lds4[i] = cls4[g];
  }
  __syncthreads();

  if (tid >= nloc) return;
  const int a = a0 + tid;
  const int tg = b * A_N + a;
  float* lg = lds + tid * C_N;

  float m = lg[0];
  for (int c = 1; c < C_N; ++c) m = fmaxf(m, lg[c]);
  float s = 0.0f;
  for (int c = 0; c < C_N; ++c) {
    float e = expf(lg[c] - m);
    s += e;
    lg[c] = e;
  }
  for (int c = 1; c < C_N; ++c)
    probs_t[((size_t)b * FG_N + (c - 1)) * A_N + a] = lg[c] / s;

  float4 rl = *(const float4*)(reg + (size_t)tg * 4);
  float4 an = *(const float4*)(anc + (size_t)a * 4);
  float wa = an.z - an.x;
  float ha = an.w - an.y;
  float cxa = an.x + 0.5f * wa;
  float cya = an.y + 0.5f * ha;
  float dx = rl.x / 10.0f;
  float dy = rl.y / 10.0f;
  const float clipv = 4.135166556742356f;   // log(1000/16)
  float dw = fminf(rl.z / 5.0f, clipv);
  float dh = fminf(rl.w / 5.0f, clipv);
  float t1 = dx * wa;  float cx = t1 + cxa;
  float t2 = dy * ha;  float cy = t2 + cya;
  float w = expf(dw) * wa;
  float h = expf(dh) * ha;
  float4 out;
  out.x = fminf(fmaxf(cx - 0.5f * w, 0.0f), 300.0f);
  out.y = fminf(fmaxf(cy - 0.5f * h, 0.0f), 300.0f);
  out.z = fminf(fmaxf(cx + 0.5f * w, 0.0f), 300.0f);
  out.w = fminf(fmaxf(cy + 0.5f * h, 0.0f), 300.0f);
  *(float4*)(boxes + (size_t)tg * 4) = out;
}

// ---------------------------------------------------------------------------
// shared helper: descending rank-select over a 256-chunked histogram
// ---------------------------------------------------------------------------
__device__ __forceinline__ void scan_select(int* hist, int nbins, int need,
                                            int tid, int* chunk, int* res)
{
  int per = nbins >> 8;            // 4096 -> 16, 256 -> 1
  int s = 0;
  for (int i = 0; i < per; ++i) s += hist[tid * per + i];
  chunk[tid] = s;
  __syncthreads();
  if (tid == 0) {
    int cum = 0;
    for (int t2 = 255; t2 >= 0; --t2) { int v = chunk[t2]; chunk[t2] = cum; cum += v; }
  }
  __syncthreads();
  int cum = chunk[tid];            // count in strictly-higher chunks
  for (int i = per - 1; i >= 0; --i) {
    int bn = tid * per + i;
    int h = hist[bn];
    if (cum < need && need <= cum + h) { res[0] = bn; res[1] = cum; }
    cum += h;
  }
  __syncthreads();
}

// ---------------------------------------------------------------------------
// K23: FUSED top-400 + NMS, one block (4 waves) per (image, fg-class).
//   Phase 1 (R9 k2): histogram rank-scatter over monotone 12-bit score bins
//   (float bits [25:14], scores in (0.01,1]); per-bin insertion sorts give
//   exact (score desc, anchor asc) order in LDS `sorted`. Legacy
//   radix+bitonic fallback if a needed bin straddles slot 1024.
//   Phase 2 (R9 k3): chunked greedy NMS consuming candidates from `sorted`
//   (no global topk round-trip). Kept arrays overlay the dead cnt[] region;
//   resolve reads box j from a wave-0-staged LDS chunk (ds_read_b128
//   broadcast) instead of 5 shuffles. IoU decisions bit-match the reference
//   (same operand order, division-free compare + wave-uniform exact-div
//   fallback band). Fusion removes the inter-kernel barrier so top-k-phase
//   blocks overlap NMS-phase blocks across the grid.
// ---------------------------------------------------------------------------
__global__ __launch_bounds__(256) void k23_topk_nms(
    const float* __restrict__ probs_t, const float* __restrict__ boxes,
    int* __restrict__ topk_anchor,
    unsigned long long* __restrict__ kept_key, int* __restrict__ kept_cnt)
{
#pragma clang fp contract(off)
  __shared__ __align__(16) int cnt[4096];        // 16.4 KB, reused in phase 2
  __shared__ unsigned long long sorted[1024];    //  8.2 KB
  __shared__ int chunk[256];                     //  1 KB
  __shared__ int res[2];
  __shared__ int s_total;
  __shared__ int s_bad;
  __shared__ int s_lcnt;
  __shared__ unsigned long long s_supm[4];
  __shared__ int s_nk;
  const int task = blockIdx.x;
  const int tid = threadIdx.x;
  const float* sc = probs_t + (size_t)task * A_N;

  // ======================= Phase 1: exact top-400 =========================
  for (int i = tid; i < 4096; i += 256) cnt[i] = 0;
  if (tid == 0) s_bad = 0;
  __syncthreads();

  for (int a = tid; a < A_N; a += 256) {
    float p = sc[a];
    if (p > 0.01f)
      atomicAdd(&cnt[(__float_as_uint(p) >> 14) & 0xFFFu], 1);
  }
  __syncthreads();
  {
    int s = 0;
    for (int i = 0; i < 16; ++i) s += cnt[tid * 16 + i];
    chunk[tid] = s;
  }
  __syncthreads();
  if (tid == 0) {
    int run = 0;
    for (int c = 255; c >= 0; --c) { int v = chunk[c]; chunk[c] = run; run += v; }
    s_total = run;
  }
  __syncthreads();
  {
    int acc = chunk[tid];
    for (int i = 15; i >= 0; --i) {
      int bn = tid * 16 + i;
      int h = cnt[bn];
      cnt[bn] = acc;
      acc += h;
    }
  }
  __syncthreads();
  const int total = s_total;
  const int ksel = total < K_TOP ? total : K_TOP;

  for (int a = tid; a < A_N; a += 256) {
    float p = sc[a];
    if (p > 0.01f) {
      unsigned k = __float_as_uint(p);
      int pos = atomicAdd(&cnt[(k >> 14) & 0xFFFu], 1);
      if (pos < 1024)
        sorted[pos] = ((unsigned long long)k << 32) | (unsigned)(0xFFFFFFFFu - (unsigned)a);
    }
  }
  __syncthreads();
  for (int i = 0; i < 16; ++i) {
    int bn = tid * 16 + i;
    int end0 = cnt[bn];
    int start = (bn < 4095) ? cnt[bn + 1] : 0;
    int cb = end0 - start;
    if (cb > 1 && start < K_TOP) {
      if (end0 > 1024) { s_bad = 1; continue; }
      for (int q = start + 1; q < end0; ++q) {
        unsigned long long v = sorted[q];
        int j = q - 1;
        while (j >= start && sorted[j] < v) { sorted[j + 1] = sorted[j]; --j; }
        sorted[j + 1] = v;
      }
    }
  }
  __syncthreads();

  if (s_bad) {
    // ---------- exact legacy fallback: radix select + bitonic 1024 --------
    for (int i = tid; i < 4096; i += 256) cnt[i] = 0;
    __syncthreads();
    for (int a = tid; a < A_N; a += 256) {
      float p = sc[a];
      if (p > 0.01f) atomicAdd(&cnt[__float_as_uint(p) >> 20], 1);
    }
    __syncthreads();
    int need = K_TOP;
    scan_select(cnt, 4096, need, tid, chunk, res);
    const unsigned b1 = (unsigned)res[0];
    const int above1 = res[1];
    const int in1 = cnt[b1];
    __syncthreads();
    unsigned cutoff;
    if (above1 + in1 <= 1024) {
      cutoff = b1 << 20;
    } else {
      need -= above1;
      for (int i = tid; i < 4096; i += 256) cnt[i] = 0;
      __syncthreads();
      for (int a = tid; a < A_N; a += 256) {
        float p = sc[a];
        if (p > 0.01f) {
          unsigned k = __float_as_uint(p);
          if ((k >> 20) == b1) atomicAdd(&cnt[(k >> 8) & 0xFFFu], 1);
        }
      }
      __syncthreads();
      scan_select(cnt, 4096, need, tid, chunk, res);
      const unsigned b2 = (unsigned)res[0];
      need -= res[1];
      const unsigned pre12 = (b1 << 12) | b2;
      __syncthreads();
      cnt[tid] = 0;
      __syncthreads();
      for (int a = tid; a < A_N; a += 256) {
        float p = sc[a];
        if (p > 0.01f) {
          unsigned k = __float_as_uint(p);
          if ((k >> 8) == pre12) atomicAdd(&cnt[k & 0xFFu], 1);
        }
      }
      __syncthreads();
      scan_select(cnt, 256, need, tid, chunk, res);
      cutoff = (pre12 << 8) | (unsigned)res[0];
      __syncthreads();
    }
    if (tid == 0) s_lcnt = 0;
    __syncthreads();
    for (int a = tid; a < A_N; a += 256) {
      float p = sc[a];
      if (p > 0.01f) {
        unsigned k = __float_as_uint(p);
        if (k >= cutoff) {
          int pos = atomicAdd(&s_lcnt, 1);
          if (pos < 1024)
            sorted[pos] = ((unsigned long long)k << 32) | (unsigned)(0xFFFFFFFFu - (unsigned)a);
        }
      }
    }
    __syncthreads();
    const int n = s_lcnt < 1024 ? s_lcnt : 1024;
    const int W = (n <= 512) ? 512 : 1024;
    for (int i = tid; i < W; i += 256) if (i >= n) sorted[i] = 0ULL;
    __syncthreads();
    for (int kk = 2; kk <= W; kk <<= 1) {
      for (int jj = kk >> 1; jj > 0; jj >>= 1) {
        for (int i = tid; i < W; i += 256) {
          int ix = i ^ jj;
          if (ix > i) {
            unsigned long long va = sorted[i], vb = sorted[ix];
            bool desc = ((i & kk) == 0);
            if (desc ? (va < vb) : (va > vb)) { sorted[i] = vb; sorted[ix] = va; }
          }
        }
        __syncthreads();
      }
    }
  }

  // anchors for k5's flat->anchor lookup
  for (int r = tid; r < ksel; r += 256) {
    unsigned long long v = sorted[r];
    topk_anchor[(size_t)task * K_TOP + r] =
        (int)(0xFFFFFFFFu - (unsigned)(v & 0xFFFFFFFFull));
  }
  if (tid == 0) s_nk = 0;
  __syncthreads();

  // ========================= Phase 2: greedy NMS ==========================
  // overlay kept arrays + chunk staging onto the dead cnt[] region
  float4* keptb  = (float4*)cnt;               // bytes [0, 3200)
  float*  kepta  = (float*)(cnt + 800);        // bytes [3200, 4000)
  int*    keptr  = cnt + 1000;                 // bytes [4000, 4800)
  float4* chunkb = (float4*)(cnt + 1200);      // bytes [4800, 5824)

  const int wid  = tid >> 6;
  const int lane = tid & 63;
  const int b = task / FG_N;
  const int c = task - b * FG_N;
  const float off = (float)(c + 1) * 302.0f;
  const float* bx = boxes + (size_t)b * (A_N * 4);

  float4 nxt = make_float4(0.0f, 0.0f, 0.0f, 0.0f);
  if (lane < ksel) {
    int a0 = (int)(0xFFFFFFFFu - (unsigned)(sorted[lane] & 0xFFFFFFFFull));
    nxt = *(const float4*)(bx + (size_t)a0 * 4);
  }
  for (int c0 = 0; c0 < ksel; c0 += 64) {
    float4 cur = nxt;
    int nidx = c0 + 64 + lane;
    if (nidx < ksel) {
      int an = (int)(0xFFFFFFFFu - (unsigned)(sorted[nidx] & 0xFFFFFFFFull));
      nxt = *(const float4*)(bx + (size_t)an * 4);
    }
    const bool validc = (c0 + lane) < ksel;
    cur.x += off; cur.y += off; cur.z += off; cur.w += off;
    const float area = (cur.z - cur.x) * (cur.w - cur.y);
    const int nk = s_nk;                        // stable since last barrier
    if (wid == 0) chunkb[lane] = cur;           // same-wave LDS, no barrier

    bool sup = !validc;
    for (int k = wid; k < nk; k += 4) {
      float4 kb = keptb[k];
      float  ka = kepta[k];
      float ix1 = fmaxf(cur.x, kb.x);
      float iy1 = fmaxf(cur.y, kb.y);
      float ix2 = fminf(cur.z, kb.z);
      float iy2 = fminf(cur.w, kb.w);
      float inter = fmaxf(ix2 - ix1, 0.0f) * fmaxf(iy2 - iy1, 0.0f);
      float denom = ka + area - inter + 1e-9f;
      float thr = 0.45f * denom;
      bool s_sup = inter > thr;
      bool amb = fabsf(inter - thr) <= 1.5e-6f * thr;
      if (__ballot(amb)) {                      // wave-uniform: skip divide
        if (amb) s_sup = (inter / denom) > 0.45f;
      }
      sup = sup || s_sup;
    }
    s_supm[wid] = __ballot(sup);
    __syncthreads();

    if (wid == 0) {
      unsigned long long todo =
          ~(s_supm[0] | s_supm[1] | s_supm[2] | s_supm[3]);
      unsigned long long surv = 0ULL;
      int ns = 0;
      const int room = D_N - nk;
      while (todo) {
        if (ns == room) break;
        int j = __ffsll((unsigned long long)todo) - 1;
        surv |= 1ULL << j;
        ++ns;
        todo &= ~(1ULL << j);
        float4 bj = chunkb[j];                  // LDS broadcast, no shuffles
        float ja = (bj.z - bj.x) * (bj.w - bj.y);   // bit-equal to lane j's area
        float ix1 = fmaxf(bj.x, cur.x);
        float iy1 = fmaxf(bj.y, cur.y);
        float ix2 = fminf(bj.z, cur.z);
        float iy2 = fminf(bj.w, cur.w);
        float inter = fmaxf(ix2 - ix1, 0.0f) * fmaxf(iy2 - iy1, 0.0f);
        float denom = ja + area - inter + 1e-9f;
        float thr = 0.45f * denom;
        bool s_sup = inter > thr;
        bool amb = fabsf(inter - thr) <= 1.5e-6f * thr;
        if (__ballot(amb)) {
          if (amb) s_sup = (inter / denom) > 0.45f;
        }
        unsigned long long supj = __ballot(s_sup);
        supj &= ~(1ULL << j);                   // self-IoU = 1, mask out
        todo &= ~supj;
      }
      if ((surv >> lane) & 1ULL) {
        int my = nk + __popcll(surv & ((1ULL << lane) - 1ULL));
        keptb[my] = cur;
        kepta[my] = area;
        keptr[my] = c0 + lane;
      }
      if (lane == 0) s_nk = nk + ns;
    }
    __syncthreads();
    if (s_nk >= D_N) break;
  }

  const int nkf = s_nk;
  for (int k = tid; k < nkf; k += 256) {
    int r = keptr[k];
    unsigned sb = (unsigned)(sorted[r] >> 32);
    kept_key[(size_t)task * D_N + k] =
        ((unsigned long long)sb << 32) |
        (unsigned)(0xFFFFFFFFu - (unsigned)(c * K_TOP + r));
  }
  if (tid == 0) kept_cnt[task] = nkf;
}

// ---------------------------------------------------------------------------
// K4: per-image global pick selection = parallel top-200 of survivor keys.
// ---------------------------------------------------------------------------
__global__ __launch_bounds__(256) void k4_sel(
    const unsigned long long* __restrict__ kept_key,
    const int* __restrict__ kept_cnt, int* __restrict__ pick_flat)
{
  __shared__ int hist[4096];
  __shared__ int chunk[256];
  __shared__ int res[2];
  __shared__ int s_lcnt;
  __shared__ int s_cnts[FG_N];
  __shared__ unsigned long long lst[1024];
  const int b = blockIdx.x;
  const int tid = threadIdx.x;
  const unsigned long long* kb = kept_key + (size_t)b * FG_N * D_N;

  if (tid < FG_N) s_cnts[tid] = kept_cnt[b * FG_N + tid];
  for (int i = tid; i < 4096; i += 256) hist[i] = 0;
  if (tid == 0) s_lcnt = 0;
  __syncthreads();

  for (int idx = tid; idx < FG_N * D_N; idx += 256) {
    int c = idx / D_N, r = idx - c * D_N;
    if (r < s_cnts[c]) {
      unsigned long long k = kb[idx];
      atomicAdd(&hist[(int)(k >> 52)], 1);
      atomicAdd(&s_lcnt, 1);
    }
  }
  __syncthreads();
  const int total = s_lcnt;
  const int npick = total < D_N ? total : D_N;
  unsigned cutoff32 = 1u;
  if (total > D_N) {
    int need = D_N;
    scan_select(hist, 4096, need, tid, chunk, res);
    const unsigned b1 = (unsigned)res[0];
    const int above1 = res[1];
    const int in1 = hist[b1];
    __syncthreads();
    if (above1 + in1 <= 1024) {
      cutoff32 = b1 << 20;
    } else {
      need -= above1;
      for (int i = tid; i < 4096; i += 256) hist[i] = 0;
      __syncthreads();
      for (int idx = tid; idx < FG_N * D_N; idx += 256) {
        int c = idx / D_N, r = idx - c * D_N;
        if (r < s_cnts[c]) {
          unsigned long long k = kb[idx];
          if ((unsigned)(k >> 52) == b1)
            atomicAdd(&hist[(int)((k >> 40) & 0xFFFull)], 1);
        }
      }
      __syncthreads();
      scan_select(hist, 4096, need, tid, chunk, res);
      const unsigned b2 = (unsigned)res[0];
      need -= res[1];
      const unsigned pre12 = (b1 << 12) | b2;
      __syncthreads();
      hist[tid] = 0;
      __syncthreads();
      for (int idx = tid; idx < FG_N * D_N; idx += 256) {
        int c = idx / D_N, r = idx - c * D_N;
        if (r < s_cnts[c]) {
          unsigned long long k = kb[idx];
          if ((unsigned)(k >> 40) == pre12)
            atomicAdd(&hist[(int)((k >> 32) & 0xFFull)], 1);
        }
      }
      __syncthreads();
      scan_select(hist, 256, need, tid, chunk, res);
      cutoff32 = (pre12 << 8) | (unsigned)res[0];
      __syncthreads();
    }
  }
  if (tid == 0) s_lcnt = 0;
  __syncthreads();
  const unsigned long long cutkey = (unsigned long long)cutoff32 << 32;
  for (int idx = tid; idx < FG_N * D_N; idx += 256) {
    int c = idx / D_N, r = idx - c * D_N;
    if (r < s_cnts[c]) {
      unsigned long long k = kb[idx];
      if (k >= cutkey) {
        int pos = atomicAdd(&s_lcnt, 1);
        if (pos < 1024) lst[pos] = k;
      }
    }
  }
  __syncthreads();
  const int n = s_lcnt < 1024 ? s_lcnt : 1024;
  const int W = (n <= 256) ? 256 : (n <= 512) ? 512 : 1024;
  for (int i = tid; i < W; i += 256) if (i >= n) lst[i] = 0ULL;
  __syncthreads();
  for (int kk = 2; kk <= W; kk <<= 1) {
    for (int jj = kk >> 1; jj > 0; jj >>= 1) {
      for (int i = tid; i < W; i += 256) {
        int ix = i ^ jj;
        if (ix > i) {
          unsigned long long va = lst[i], vb = lst[ix];
          bool desc = ((i & kk) == 0);
          if (desc ? (va < vb) : (va > vb)) { lst[i] = vb; lst[ix] = va; }
        }
      }
      __syncthreads();
    }
  }
  for (int i = tid; i < D_N; i += 256) {
    int v = -1;
    if (i < npick)
      v = (int)(0xFFFFFFFFu - (unsigned)(lst[i] & 0xFFFFFFFFull));
    pick_flat[b * D_N + i] = v;
  }
}

// ---------------------------------------------------------------------------
// K5: one wave per pick; packed u64 butterfly top-2 over 90 classes.
// ---------------------------------------------------------------------------
__global__ __launch_bounds__(256) void k5_out(
    const float* __restrict__ probs_t, const float* __restrict__ boxes,
    const int* __restrict__ topk_anchor, const int* __restrict__ pick_flat,
    float* __restrict__ out)
{
  const int wid  = threadIdx.x >> 6;
  const int lane = threadIdx.x & 63;
  const int pick = blockIdx.x * 4 + wid;
  const int b = pick / D_N;
  float* ob = out + (size_t)pick * 4;
  float* os = out + (size_t)B_N * D_N * 4 + (size_t)pick * 2;
  float* ol = out + (size_t)B_N * D_N * 6 + (size_t)pick * 2;
  const int flat = pick_flat[pick];
  if (flat < 0) {
    if (lane == 0) {
      ob[0] = 0.0f; ob[1] = 0.0f; ob[2] = 0.0f; ob[3] = 0.0f;
      os[0] = 0.0f; os[1] = 0.0f;
      ol[0] = 0.0f; ol[1] = 0.0f;
    }
    return;
  }
  const int c = flat / K_TOP;
  const int r = flat - c * K_TOP;
  const int anchor = topk_anchor[((size_t)b * FG_N + c) * K_TOP + r];
  const float* pp = probs_t + (size_t)b * FG_N * A_N + anchor;

  unsigned long long hi, lo = 0ULL;
  {
    float p = pp[(size_t)lane * A_N];
    hi = ((unsigned long long)__float_as_uint(p) << 32) | (0xFFFFFFFFu - (unsigned)lane);
  }
  if (lane + 64 < FG_N) {
    float p = pp[(size_t)(lane + 64) * A_N];
    unsigned long long k2 = ((unsigned long long)__float_as_uint(p) << 32) |
                            (0xFFFFFFFFu - (unsigned)(lane + 64));
    if (k2 > hi) { lo = hi; hi = k2; } else lo = k2;
  }
#pragma unroll
  for (int d = 1; d < 64; d <<= 1) {
    unsigned long long oh = __shfl_xor(hi, d, 64);
    unsigned long long ol2 = __shfl_xor(lo, d, 64);
    unsigned long long nh = hi > oh ? hi : oh;
    unsigned long long mn = hi > oh ? oh : hi;
    unsigned long long ml = lo > ol2 ? lo : ol2;
    hi = nh;
    lo = mn > ml ? mn : ml;
  }
  if (lane == 0) {
    float4 bp = *(const float4*)(boxes + ((size_t)b * A_N + anchor) * 4);
    *(float4*)ob = bp;
    unsigned cc1 = 0xFFFFFFFFu - (unsigned)(hi & 0xFFFFFFFFull);
    unsigned cc2 = 0xFFFFFFFFu - (unsigned)(lo & 0xFFFFFFFFull);
    os[0] = __uint_as_float((unsigned)(hi >> 32));
    os[1] = __uint_as_float((unsigned)(lo >> 32));
    ol[0] = (float)(cc1 + 1);
    ol[1] = (float)(cc2 + 1);
  }
}

// ---------------------------------------------------------------------------
extern "C" void kernel_launch(void* const* d_in, const int* in_sizes, int n_in,
                              void* d_out, int out_size, void* d_ws, size_t ws_size,
                              hipStream_t stream)
{
  (void)in_sizes; (void)n_in; (void)out_size; (void)ws_size;
  const float* cls = (const float*)d_in[0];
  const float* reg = (const float*)d_in[1];
  const float* anc = (const float*)d_in[2];

  char* w = (char*)d_ws;
  size_t off = 0;
  auto carve = [&](size_t bytes) -> char* {
    char* p = w + off;
    off += (bytes + 255) & ~(size_t)255;
    return p;
  };
  float* probs_t                = (float*)carve((size_t)B_N * FG_N * A_N * 4);
  float* boxes                  = (float*)carve((size_t)B_N * A_N * 4 * 4);
  int* topk_anchor              = (int*)carve((size_t)NTASK * K_TOP * 4);
  unsigned long long* kept_key  = (unsigned long long*)carve((size_t)NTASK * D_N * 8);
  int* kept_cnt                 = (int*)carve((size_t)NTASK * 4);
  int* pick_flat                = (int*)carve((size_t)B_N * D_N * 4);

  hipLaunchKernelGGL(k1_softmax_decode, dim3(B_N * K1_NBLK), dim3(K1_APB), 0, stream,
                     cls, reg, anc, probs_t, boxes);
  hipLaunchKernelGGL(k23_topk_nms, dim3(NTASK), dim3(256), 0, stream,
                     probs_t, boxes, topk_anchor, kept_key, kept_cnt);
  hipLaunchKernelGGL(k4_sel, dim3(B_N), dim3(256), 0, stream,
                     kept_key, kept_cnt, pick_flat);
  hipLaunchKernelGGL(k5_out, dim3(B_N * D_N / 4), dim3(256), 0, stream,
                     probs_t, boxes, topk_anchor, pick_flat, (float*)d_out);
}

// Round 12
// 301.818 us; speedup vs baseline: 1.1541x; 1.0681x over previous
//
#include <hip/hip_runtime.h>
#include <cstdint>
#include <cstddef>

#define B_N   16
#define A_N   8732
#define C_N   91
#define FG_N  90
#define K_TOP 400
#define D_N   200
#define NTASK (B_N * FG_N)   // 1440
#define K1_APB 128           // anchors per block in k1
#define K1_NBLK ((A_N + K1_APB - 1) / K1_APB)   // 69

// ---------------------------------------------------------------------------
// K1: softmax + decode, LDS-staged (coalesced float4 slab load, expf once).
// ---------------------------------------------------------------------------
__global__ __launch_bounds__(128) void k1_softmax_decode(
    const float* __restrict__ cls, const float* __restrict__ reg,
    const float* __restrict__ anc, float* __restrict__ probs_t,
    float* __restrict__ boxes)
{
#pragma clang fp contract(off)
  __shared__ float4 lds4[(K1_APB * C_N + 3) / 4];   // 46.6 KB
  float* lds = (float*)lds4;
  const int bb = blockIdx.x;
  const int b = bb / K1_NBLK;
  const int blk = bb - b * K1_NBLK;
  const int a0 = blk * K1_APB;
  const int nloc = (A_N - a0) < K1_APB ? (A_N - a0) : K1_APB;
  const int tid = threadIdx.x;

  const size_t gbase_f4 = ((size_t)(b * A_N + a0) * C_N) >> 2;
  const size_t TOT_F4 = ((size_t)B_N * A_N * C_N) >> 2;
  const float4* cls4 = (const float4*)cls;
  constexpr int NF4 = (K1_APB * C_N) / 4;           // 2912
  for (int i = tid; i < NF4; i += K1_APB) {
    size_t g = gbase_f4 + i;
    if (g < TOT_F4) lds4[i] = cls4[g];
  }
  __syncthreads();

  if (tid >= nloc) return;
  const int a = a0 + tid;
  const int tg = b * A_N + a;
  float* lg = lds + tid * C_N;

  float m = lg[0];
  for (int c = 1; c < C_N; ++c) m = fmaxf(m, lg[c]);
  float s = 0.0f;
  for (int c = 0; c < C_N; ++c) {
    float e = expf(lg[c] - m);
    s += e;
    lg[c] = e;
  }
  for (int c = 1; c < C_N; ++c)
    probs_t[((size_t)b * FG_N + (c - 1)) * A_N + a] = lg[c] / s;

  float4 rl = *(const float4*)(reg + (size_t)tg * 4);
  float4 an = *(const float4*)(anc + (size_t)a * 4);
  float wa = an.z - an.x;
  float ha = an.w - an.y;
  float cxa = an.x + 0.5f * wa;
  float cya = an.y + 0.5f * ha;
  float dx = rl.x / 10.0f;
  float dy = rl.y / 10.0f;
  const float clipv = 4.135166556742356f;   // log(1000/16)
  float dw = fminf(rl.z / 5.0f, clipv);
  float dh = fminf(rl.w / 5.0f, clipv);
  float t1 = dx * wa;  float cx = t1 + cxa;
  float t2 = dy * ha;  float cy = t2 + cya;
  float w = expf(dw) * wa;
  float h = expf(dh) * ha;
  float4 out;
  out.x = fminf(fmaxf(cx - 0.5f * w, 0.0f), 300.0f);
  out.y = fminf(fmaxf(cy - 0.5f * h, 0.0f), 300.0f);
  out.z = fminf(fmaxf(cx + 0.5f * w, 0.0f), 300.0f);
  out.w = fminf(fmaxf(cy + 0.5f * h, 0.0f), 300.0f);
  *(float4*)(boxes + (size_t)tg * 4) = out;
}

// ---------------------------------------------------------------------------
// shared helper: descending rank-select over a 256-chunked histogram
// ---------------------------------------------------------------------------
__device__ __forceinline__ void scan_select(int* hist, int nbins, int need,
                                            int tid, int* chunk, int* res)
{
  int per = nbins >> 8;            // 4096 -> 16, 256 -> 1
  int s = 0;
  for (int i = 0; i < per; ++i) s += hist[tid * per + i];
  chunk[tid] = s;
  __syncthreads();
  if (tid == 0) {
    int cum = 0;
    for (int t2 = 255; t2 >= 0; --t2) { int v = chunk[t2]; chunk[t2] = cum; cum += v; }
  }
  __syncthreads();
  int cum = chunk[tid];            // count in strictly-higher chunks
  for (int i = per - 1; i >= 0; --i) {
    int bn = tid * per + i;
    int h = hist[bn];
    if (cum < need && need <= cum + h) { res[0] = bn; res[1] = cum; }
    cum += h;
  }
  __syncthreads();
}

// ---------------------------------------------------------------------------
// K23: FUSED top-400 + NMS, one block (4 waves) per (image, fg-class).
//   Phase 1: histogram rank-scatter over monotone 12-bit score bins (float
//   bits [25:14], scores in (0.01,1]), both global passes vectorized as
//   float4 (A_N = 4*2183, 16B-aligned base). Per-bin insertion sorts give
//   exact (score desc, anchor asc) order in LDS `sorted`. Legacy
//   radix+bitonic fallback if a needed bin straddles slot 1024.
//   Phase 2: chunked greedy NMS from `sorted` (kept arrays overlay the dead
//   cnt[] region; resolve reads box j from a wave-0-staged LDS chunk).
//   IoU decisions bit-match the reference (same operand order, division-free
//   compare + wave-uniform exact-div fallback band).
// ---------------------------------------------------------------------------
__global__ __launch_bounds__(256) void k23_topk_nms(
    const float* __restrict__ probs_t, const float* __restrict__ boxes,
    int* __restrict__ topk_anchor,
    unsigned long long* __restrict__ kept_key, int* __restrict__ kept_cnt)
{
#pragma clang fp contract(off)
  __shared__ __align__(16) int cnt[4096];        // 16.4 KB, reused in phase 2
  __shared__ unsigned long long sorted[1024];    //  8.2 KB
  __shared__ int chunk[256];                     //  1 KB
  __shared__ int res[2];
  __shared__ int s_total;
  __shared__ int s_bad;
  __shared__ int s_lcnt;
  __shared__ unsigned long long s_supm[4];
  __shared__ int s_nk;
  const int task = blockIdx.x;
  const int tid = threadIdx.x;
  const float* sc = probs_t + (size_t)task * A_N;
  const float4* sc4 = (const float4*)sc;
  constexpr int NV4 = A_N >> 2;                  // 2183

  // ======================= Phase 1: exact top-400 =========================
  for (int i = tid; i < 4096; i += 256) cnt[i] = 0;
  if (tid == 0) s_bad = 0;
  __syncthreads();

  for (int i = tid; i < NV4; i += 256) {
    float4 p4 = sc4[i];
    if (p4.x > 0.01f) atomicAdd(&cnt[(__float_as_uint(p4.x) >> 14) & 0xFFFu], 1);
    if (p4.y > 0.01f) atomicAdd(&cnt[(__float_as_uint(p4.y) >> 14) & 0xFFFu], 1);
    if (p4.z > 0.01f) atomicAdd(&cnt[(__float_as_uint(p4.z) >> 14) & 0xFFFu], 1);
    if (p4.w > 0.01f) atomicAdd(&cnt[(__float_as_uint(p4.w) >> 14) & 0xFFFu], 1);
  }
  __syncthreads();
  {
    int s = 0;
    for (int i = 0; i < 16; ++i) s += cnt[tid * 16 + i];
    chunk[tid] = s;
  }
  __syncthreads();
  if (tid == 0) {
    int run = 0;
    for (int c = 255; c >= 0; --c) { int v = chunk[c]; chunk[c] = run; run += v; }
    s_total = run;
  }
  __syncthreads();
  {
    int acc = chunk[tid];
    for (int i = 15; i >= 0; --i) {
      int bn = tid * 16 + i;
      int h = cnt[bn];
      cnt[bn] = acc;
      acc += h;
    }
  }
  __syncthreads();
  const int total = s_total;
  const int ksel = total < K_TOP ? total : K_TOP;

  for (int i = tid; i < NV4; i += 256) {
    float4 p4 = sc4[i];
    const unsigned a0 = (unsigned)(i * 4);
    if (p4.x > 0.01f) {
      unsigned k = __float_as_uint(p4.x);
      int pos = atomicAdd(&cnt[(k >> 14) & 0xFFFu], 1);
      if (pos < 1024)
        sorted[pos] = ((unsigned long long)k << 32) | (0xFFFFFFFFu - a0);
    }
    if (p4.y > 0.01f) {
      unsigned k = __float_as_uint(p4.y);
      int pos = atomicAdd(&cnt[(k >> 14) & 0xFFFu], 1);
      if (pos < 1024)
        sorted[pos] = ((unsigned long long)k << 32) | (0xFFFFFFFFu - (a0 + 1));
    }
    if (p4.z > 0.01f) {
      unsigned k = __float_as_uint(p4.z);
      int pos = atomicAdd(&cnt[(k >> 14) & 0xFFFu], 1);
      if (pos < 1024)
        sorted[pos] = ((unsigned long long)k << 32) | (0xFFFFFFFFu - (a0 + 2));
    }
    if (p4.w > 0.01f) {
      unsigned k = __float_as_uint(p4.w);
      int pos = atomicAdd(&cnt[(k >> 14) & 0xFFFu], 1);
      if (pos < 1024)
        sorted[pos] = ((unsigned long long)k << 32) | (0xFFFFFFFFu - (a0 + 3));
    }
  }
  __syncthreads();
  for (int i = 0; i < 16; ++i) {
    int bn = tid * 16 + i;
    int end0 = cnt[bn];
    int start = (bn < 4095) ? cnt[bn + 1] : 0;
    int cb = end0 - start;
    if (cb > 1 && start < K_TOP) {
      if (end0 > 1024) { s_bad = 1; continue; }   // drop requires cb>624
      for (int q = start + 1; q < end0; ++q) {
        unsigned long long v = sorted[q];
        int j = q - 1;
        while (j >= start && sorted[j] < v) { sorted[j + 1] = sorted[j]; --j; }
        sorted[j + 1] = v;
      }
    }
  }
  __syncthreads();

  if (s_bad) {
    // ---------- exact legacy fallback: radix select + bitonic 1024 --------
    for (int i = tid; i < 4096; i += 256) cnt[i] = 0;
    __syncthreads();
    for (int a = tid; a < A_N; a += 256) {
      float p = sc[a];
      if (p > 0.01f) atomicAdd(&cnt[__float_as_uint(p) >> 20], 1);
    }
    __syncthreads();
    int need = K_TOP;
    scan_select(cnt, 4096, need, tid, chunk, res);
    const unsigned b1 = (unsigned)res[0];
    const int above1 = res[1];
    const int in1 = cnt[b1];
    __syncthreads();
    unsigned cutoff;
    if (above1 + in1 <= 1024) {
      cutoff = b1 << 20;
    } else {
      need -= above1;
      for (int i = tid; i < 4096; i += 256) cnt[i] = 0;
      __syncthreads();
      for (int a = tid; a < A_N; a += 256) {
        float p = sc[a];
        if (p > 0.01f) {
          unsigned k = __float_as_uint(p);
          if ((k >> 20) == b1) atomicAdd(&cnt[(k >> 8) & 0xFFFu], 1);
        }
      }
      __syncthreads();
      scan_select(cnt, 4096, need, tid, chunk, res);
      const unsigned b2 = (unsigned)res[0];
      need -= res[1];
      const unsigned pre12 = (b1 << 12) | b2;
      __syncthreads();
      cnt[tid] = 0;
      __syncthreads();
      for (int a = tid; a < A_N; a += 256) {
        float p = sc[a];
        if (p > 0.01f) {
          unsigned k = __float_as_uint(p);
          if ((k >> 8) == pre12) atomicAdd(&cnt[k & 0xFFu], 1);
        }
      }
      __syncthreads();
      scan_select(cnt, 256, need, tid, chunk, res);
      cutoff = (pre12 << 8) | (unsigned)res[0];
      __syncthreads();
    }
    if (tid == 0) s_lcnt = 0;
    __syncthreads();
    for (int a = tid; a < A_N; a += 256) {
      float p = sc[a];
      if (p > 0.01f) {
        unsigned k = __float_as_uint(p);
        if (k >= cutoff) {
          int pos = atomicAdd(&s_lcnt, 1);
          if (pos < 1024)
            sorted[pos] = ((unsigned long long)k << 32) | (unsigned)(0xFFFFFFFFu - (unsigned)a);
        }
      }
    }
    __syncthreads();
    const int n = s_lcnt < 1024 ? s_lcnt : 1024;
    const int W = (n <= 512) ? 512 : 1024;
    for (int i = tid; i < W; i += 256) if (i >= n) sorted[i] = 0ULL;
    __syncthreads();
    for (int kk = 2; kk <= W; kk <<= 1) {
      for (int jj = kk >> 1; jj > 0; jj >>= 1) {
        for (int i = tid; i < W; i += 256) {
          int ix = i ^ jj;
          if (ix > i) {
            unsigned long long va = sorted[i], vb = sorted[ix];
            bool desc = ((i & kk) == 0);
            if (desc ? (va < vb) : (va > vb)) { sorted[i] = vb; sorted[ix] = va; }
          }
        }
        __syncthreads();
      }
    }
  }

  // anchors for k5's flat->anchor lookup
  for (int r = tid; r < ksel; r += 256) {
    unsigned long long v = sorted[r];
    topk_anchor[(size_t)task * K_TOP + r] =
        (int)(0xFFFFFFFFu - (unsigned)(v & 0xFFFFFFFFull));
  }
  if (tid == 0) s_nk = 0;
  __syncthreads();

  // ========================= Phase 2: greedy NMS ==========================
  // overlay kept arrays + chunk staging onto the dead cnt[] region
  float4* keptb  = (float4*)cnt;               // bytes [0, 3200)
  float*  kepta  = (float*)(cnt + 800);        // bytes [3200, 4000)
  int*    keptr  = cnt + 1000;                 // bytes [4000, 4800)
  float4* chunkb = (float4*)(cnt + 1200);      // bytes [4800, 5824)

  const int wid  = tid >> 6;
  const int lane = tid & 63;
  const int b = task / FG_N;
  const int c = task - b * FG_N;
  const float off = (float)(c + 1) * 302.0f;
  const float* bx = boxes + (size_t)b * (A_N * 4);

  float4 nxt = make_float4(0.0f, 0.0f, 0.0f, 0.0f);
  if (lane < ksel) {
    int a0 = (int)(0xFFFFFFFFu - (unsigned)(sorted[lane] & 0xFFFFFFFFull));
    nxt = *(const float4*)(bx + (size_t)a0 * 4);
  }
  for (int c0 = 0; c0 < ksel; c0 += 64) {
    float4 cur = nxt;
    int nidx = c0 + 64 + lane;
    if (nidx < ksel) {
      int an = (int)(0xFFFFFFFFu - (unsigned)(sorted[nidx] & 0xFFFFFFFFull));
      nxt = *(const float4*)(bx + (size_t)an * 4);
    }
    const bool validc = (c0 + lane) < ksel;
    cur.x += off; cur.y += off; cur.z += off; cur.w += off;
    const float area = (cur.z - cur.x) * (cur.w - cur.y);
    const int nk = s_nk;                        // stable since last barrier
    if (wid == 0) chunkb[lane] = cur;           // same-wave LDS, no barrier

    bool sup = !validc;
    for (int k = wid; k < nk; k += 4) {
      float4 kb = keptb[k];
      float  ka = kepta[k];
      float ix1 = fmaxf(cur.x, kb.x);
      float iy1 = fmaxf(cur.y, kb.y);
      float ix2 = fminf(cur.z, kb.z);
      float iy2 = fminf(cur.w, kb.w);
      float inter = fmaxf(ix2 - ix1, 0.0f) * fmaxf(iy2 - iy1, 0.0f);
      float denom = ka + area - inter + 1e-9f;
      float thr = 0.45f * denom;
      bool s_sup = inter > thr;
      bool amb = fabsf(inter - thr) <= 1.5e-6f * thr;
      if (__ballot(amb)) {                      // wave-uniform: skip divide
        if (amb) s_sup = (inter / denom) > 0.45f;
      }
      sup = sup || s_sup;
    }
    s_supm[wid] = __ballot(sup);
    __syncthreads();

    if (wid == 0) {
      unsigned long long todo =
          ~(s_supm[0] | s_supm[1] | s_supm[2] | s_supm[3]);
      unsigned long long surv = 0ULL;
      int ns = 0;
      const int room = D_N - nk;
      while (todo) {
        if (ns == room) break;
        int j = __ffsll((unsigned long long)todo) - 1;
        surv |= 1ULL << j;
        ++ns;
        todo &= ~(1ULL << j);
        float4 bj = chunkb[j];                  // LDS broadcast, no shuffles
        float ja = (bj.z - bj.x) * (bj.w - bj.y);   // bit-equal to lane j's area
        float ix1 = fmaxf(bj.x, cur.x);
        float iy1 = fmaxf(bj.y, cur.y);
        float ix2 = fminf(bj.z, cur.z);
        float iy2 = fminf(bj.w, cur.w);
        float inter = fmaxf(ix2 - ix1, 0.0f) * fmaxf(iy2 - iy1, 0.0f);
        float denom = ja + area - inter + 1e-9f;
        float thr = 0.45f * denom;
        bool s_sup = inter > thr;
        bool amb = fabsf(inter - thr) <= 1.5e-6f * thr;
        if (__ballot(amb)) {
          if (amb) s_sup = (inter / denom) > 0.45f;
        }
        unsigned long long supj = __ballot(s_sup);
        supj &= ~(1ULL << j);                   // self-IoU = 1, mask out
        todo &= ~supj;
      }
      if ((surv >> lane) & 1ULL) {
        int my = nk + __popcll(surv & ((1ULL << lane) - 1ULL));
        keptb[my] = cur;
        kepta[my] = area;
        keptr[my] = c0 + lane;
      }
      if (lane == 0) s_nk = nk + ns;
    }
    __syncthreads();
    if (s_nk >= D_N) break;
  }

  const int nkf = s_nk;
  for (int k = tid; k < nkf; k += 256) {
    int r = keptr[k];
    unsigned sb = (unsigned)(sorted[r] >> 32);
    kept_key[(size_t)task * D_N + k] =
        ((unsigned long long)sb << 32) |
        (unsigned)(0xFFFFFFFFu - (unsigned)(c * K_TOP + r));
  }
  if (tid == 0) kept_cnt[task] = nkf;
}

// ---------------------------------------------------------------------------
// K4: per-image top-200 of survivor keys via histogram rank-scatter.
//     Score bits live in u64 key bits [57:46] -> same monotone 12-bit bin
//     (scores in (0.01,1]). Histogram + in-place descending prefix +
//     scatter + per-bin insertion sorts (bins with start<200). Replaces the
//     55-phase bitonic + 3 global passes. Legacy radix+bitonic fallback if
//     a needed bin straddles slot 1024 (requires >824 keys sharing 21 bits).
// ---------------------------------------------------------------------------
__global__ __launch_bounds__(256) void k4_sel(
    const unsigned long long* __restrict__ kept_key,
    const int* __restrict__ kept_cnt, int* __restrict__ pick_flat)
{
  __shared__ int hist[4096];
  __shared__ unsigned long long sorted[1024];
  __shared__ int chunk[256];
  __shared__ int res[2];
  __shared__ int s_total;
  __shared__ int s_bad;
  __shared__ int s_lcnt;
  __shared__ int s_cnts[FG_N];
  const int b = blockIdx.x;
  const int tid = threadIdx.x;
  const unsigned long long* kb = kept_key + (size_t)b * FG_N * D_N;

  if (tid < FG_N) s_cnts[tid] = kept_cnt[b * FG_N + tid];
  for (int i = tid; i < 4096; i += 256) hist[i] = 0;
  if (tid == 0) s_bad = 0;
  __syncthreads();

  for (int idx = tid; idx < FG_N * D_N; idx += 256) {
    int c = idx / D_N, r = idx - c * D_N;
    if (r < s_cnts[c])
      atomicAdd(&hist[(int)((kb[idx] >> 46) & 0xFFFull)], 1);
  }
  __syncthreads();
  {
    int s = 0;
    for (int i = 0; i < 16; ++i) s += hist[tid * 16 + i];
    chunk[tid] = s;
  }
  __syncthreads();
  if (tid == 0) {
    int run = 0;
    for (int c = 255; c >= 0; --c) { int v = chunk[c]; chunk[c] = run; run += v; }
    s_total = run;
  }
  __syncthreads();
  {
    int acc = chunk[tid];
    for (int i = 15; i >= 0; --i) {
      int bn = tid * 16 + i;
      int h = hist[bn];
      hist[bn] = acc;
      acc += h;
    }
  }
  __syncthreads();
  const int total = s_total;
  const int npick = total < D_N ? total : D_N;

  for (int idx = tid; idx < FG_N * D_N; idx += 256) {
    int c = idx / D_N, r = idx - c * D_N;
    if (r < s_cnts[c]) {
      unsigned long long k = kb[idx];
      int pos = atomicAdd(&hist[(int)((k >> 46) & 0xFFFull)], 1);
      if (pos < 1024) sorted[pos] = k;
    }
  }
  __syncthreads();
  for (int i = 0; i < 16; ++i) {
    int bn = tid * 16 + i;
    int end0 = hist[bn];
    int start = (bn < 4095) ? hist[bn + 1] : 0;
    int cb = end0 - start;
    if (cb > 1 && start < D_N) {
      if (end0 > 1024) { s_bad = 1; continue; }   // drop requires cb>824
      for (int q = start + 1; q < end0; ++q) {
        unsigned long long v = sorted[q];
        int j = q - 1;
        while (j >= start && sorted[j] < v) { sorted[j + 1] = sorted[j]; --j; }
        sorted[j + 1] = v;
      }
    }
  }
  __syncthreads();

  if (s_bad) {
    // ---------- exact legacy fallback: radix select + bitonic 1024 --------
    for (int i = tid; i < 4096; i += 256) hist[i] = 0;
    if (tid == 0) s_lcnt = 0;
    __syncthreads();
    for (int idx = tid; idx < FG_N * D_N; idx += 256) {
      int c = idx / D_N, r = idx - c * D_N;
      if (r < s_cnts[c]) {
        unsigned long long k = kb[idx];
        atomicAdd(&hist[(int)(k >> 52)], 1);
      }
    }
    __syncthreads();
    unsigned cutoff32 = 1u;
    if (total > D_N) {
      int need = D_N;
      scan_select(hist, 4096, need, tid, chunk, res);
      const unsigned b1 = (unsigned)res[0];
      const int above1 = res[1];
      const int in1 = hist[b1];
      __syncthreads();
      if (above1 + in1 <= 1024) {
        cutoff32 = b1 << 20;
      } else {
        need -= above1;
        for (int i = tid; i < 4096; i += 256) hist[i] = 0;
        __syncthreads();
        for (int idx = tid; idx < FG_N * D_N; idx += 256) {
          int c = idx / D_N, r = idx - c * D_N;
          if (r < s_cnts[c]) {
            unsigned long long k = kb[idx];
            if ((unsigned)(k >> 52) == b1)
              atomicAdd(&hist[(int)((k >> 40) & 0xFFFull)], 1);
          }
        }
        __syncthreads();
        scan_select(hist, 4096, need, tid, chunk, res);
        const unsigned b2 = (unsigned)res[0];
        need -= res[1];
        const unsigned pre12 = (b1 << 12) | b2;
        __syncthreads();
        hist[tid] = 0;
        __syncthreads();
        for (int idx = tid; idx < FG_N * D_N; idx += 256) {
          int c = idx / D_N, r = idx - c * D_N;
          if (r < s_cnts[c]) {
            unsigned long long k = kb[idx];
            if ((unsigned)(k >> 40) == pre12)
              atomicAdd(&hist[(int)((k >> 32) & 0xFFull)], 1);
          }
        }
        __syncthreads();
        scan_select(hist, 256, need, tid, chunk, res);
        cutoff32 = (pre12 << 8) | (unsigned)res[0];
        __syncthreads();
      }
    }
    const unsigned long long cutkey = (unsigned long long)cutoff32 << 32;
    for (int idx = tid; idx < FG_N * D_N; idx += 256) {
      int c = idx / D_N, r = idx - c * D_N;
      if (r < s_cnts[c]) {
        unsigned long long k = kb[idx];
        if (k >= cutkey) {
          int pos = atomicAdd(&s_lcnt, 1);
          if (pos < 1024) sorted[pos] = k;
        }
      }
    }
    __syncthreads();
    const int n = s_lcnt < 1024 ? s_lcnt : 1024;
    const int W = (n <= 256) ? 256 : (n <= 512) ? 512 : 1024;
    for (int i = tid; i < W; i += 256) if (i >= n) sorted[i] = 0ULL;
    __syncthreads();
    for (int kk = 2; kk <= W; kk <<= 1) {
      for (int jj = kk >> 1; jj > 0; jj >>= 1) {
        for (int i = tid; i < W; i += 256) {
          int ix = i ^ jj;
          if (ix > i) {
            unsigned long long va = sorted[i], vb = sorted[ix];
            bool desc = ((i & kk) == 0);
            if (desc ? (va < vb) : (va > vb)) { sorted[i] = vb; sorted[ix] = va; }
          }
        }
        __syncthreads();
      }
    }
  }

  for (int i = tid; i < D_N; i += 256) {
    int v = -1;
    if (i < npick)
      v = (int)(0xFFFFFFFFu - (unsigned)(sorted[i] & 0xFFFFFFFFull));
    pick_flat[b * D_N + i] = v;
  }
}

// ---------------------------------------------------------------------------
// K5: one wave per pick; packed u64 butterfly top-2 over 90 classes.
// ---------------------------------------------------------------------------
__global__ __launch_bounds__(256) void k5_out(
    const float* __restrict__ probs_t, const float* __restrict__ boxes,
    const int* __restrict__ topk_anchor, const int* __restrict__ pick_flat,
    float* __restrict__ out)
{
  const int wid  = threadIdx.x >> 6;
  const int lane = threadIdx.x & 63;
  const int pick = blockIdx.x * 4 + wid;
  const int b = pick / D_N;
  float* ob = out + (size_t)pick * 4;
  float* os = out + (size_t)B_N * D_N * 4 + (size_t)pick * 2;
  float* ol = out + (size_t)B_N * D_N * 6 + (size_t)pick * 2;
  const int flat = pick_flat[pick];
  if (flat < 0) {
    if (lane == 0) {
      ob[0] = 0.0f; ob[1] = 0.0f; ob[2] = 0.0f; ob[3] = 0.0f;
      os[0] = 0.0f; os[1] = 0.0f;
      ol[0] = 0.0f; ol[1] = 0.0f;
    }
    return;
  }
  const int c = flat / K_TOP;
  const int r = flat - c * K_TOP;
  const int anchor = topk_anchor[((size_t)b * FG_N + c) * K_TOP + r];
  const float* pp = probs_t + (size_t)b * FG_N * A_N + anchor;

  unsigned long long hi, lo = 0ULL;
  {
    float p = pp[(size_t)lane * A_N];
    hi = ((unsigned long long)__float_as_uint(p) << 32) | (0xFFFFFFFFu - (unsigned)lane);
  }
  if (lane + 64 < FG_N) {
    float p = pp[(size_t)(lane + 64) * A_N];
    unsigned long long k2 = ((unsigned long long)__float_as_uint(p) << 32) |
                            (0xFFFFFFFFu - (unsigned)(lane + 64));
    if (k2 > hi) { lo = hi; hi = k2; } else lo = k2;
  }
#pragma unroll
  for (int d = 1; d < 64; d <<= 1) {
    unsigned long long oh = __shfl_xor(hi, d, 64);
    unsigned long long ol2 = __shfl_xor(lo, d, 64);
    unsigned long long nh = hi > oh ? hi : oh;
    unsigned long long mn = hi > oh ? oh : hi;
    unsigned long long ml = lo > ol2 ? lo : ol2;
    hi = nh;
    lo = mn > ml ? mn : ml;
  }
  if (lane == 0) {
    float4 bp = *(const float4*)(boxes + ((size_t)b * A_N + anchor) * 4);
    *(float4*)ob = bp;
    unsigned cc1 = 0xFFFFFFFFu - (unsigned)(hi & 0xFFFFFFFFull);
    unsigned cc2 = 0xFFFFFFFFu - (unsigned)(lo & 0xFFFFFFFFull);
    os[0] = __uint_as_float((unsigned)(hi >> 32));
    os[1] = __uint_as_float((unsigned)(lo >> 32));
    ol[0] = (float)(cc1 + 1);
    ol[1] = (float)(cc2 + 1);
  }
}

// ---------------------------------------------------------------------------
extern "C" void kernel_launch(void* const* d_in, const int* in_sizes, int n_in,
                              void* d_out, int out_size, void* d_ws, size_t ws_size,
                              hipStream_t stream)
{
  (void)in_sizes; (void)n_in; (void)out_size; (void)ws_size;
  const float* cls = (const float*)d_in[0];
  const float* reg = (const float*)d_in[1];
  const float* anc = (const float*)d_in[2];

  char* w = (char*)d_ws;
  size_t off = 0;
  auto carve = [&](size_t bytes) -> char* {
    char* p = w + off;
    off += (bytes + 255) & ~(size_t)255;
    return p;
  };
  float* probs_t                = (float*)carve((size_t)B_N * FG_N * A_N * 4);
  float* boxes                  = (float*)carve((size_t)B_N * A_N * 4 * 4);
  int* topk_anchor              = (int*)carve((size_t)NTASK * K_TOP * 4);
  unsigned long long* kept_key  = (unsigned long long*)carve((size_t)NTASK * D_N * 8);
  int* kept_cnt                 = (int*)carve((size_t)NTASK * 4);
  int* pick_flat                = (int*)carve((size_t)B_N * D_N * 4);

  hipLaunchKernelGGL(k1_softmax_decode, dim3(B_N * K1_NBLK), dim3(K1_APB), 0, stream,
                     cls, reg, anc, probs_t, boxes);
  hipLaunchKernelGGL(k23_topk_nms, dim3(NTASK), dim3(256), 0, stream,
                     probs_t, boxes, topk_anchor, kept_key, kept_cnt);
  hipLaunchKernelGGL(k4_sel, dim3(B_N), dim3(256), 0, stream,
                     kept_key, kept_cnt, pick_flat);
  hipLaunchKernelGGL(k5_out, dim3(B_N * D_N / 4), dim3(256), 0, stream,
                     probs_t, boxes, topk_anchor, pick_flat, (float*)d_out);
}